// Round 7
// baseline (2379.355 us; speedup 1.0000x reference)
//
#include <hip/hip_runtime.h>

#define FIN 256
#define HID 64
#define NLAYERS 5
#define NSLICE 8   // 64 features / 8 per slice

#define FMA4(ACC, S, V) { float _s = (S); ACC.x += _s*(V).x; ACC.y += _s*(V).y; ACC.z += _s*(V).z; ACC.w += _s*(V).w; }

// ---- degree histogram (int) ----
__global__ __launch_bounds__(256) void k_deg_i(const int* __restrict__ src, const int* __restrict__ dst,
                                               int* __restrict__ cs, int* __restrict__ cd, int E) {
  int i = blockIdx.x * 256 + threadIdx.x;
  if (i < E) {
    atomicAdd(&cs[src[i]], 1);
    atomicAdd(&cd[dst[i]], 1);
  }
}

__global__ __launch_bounds__(256) void k_norm(const int* __restrict__ cnt, float* __restrict__ nrm, int n) {
  int i = blockIdx.x * 256 + threadIdx.x;
  if (i < n) nrm[i] = rsqrtf(fmaxf((float)cnt[i], 1.0f));
}

// ---- CSR row allocation: wave scan + one atomic per wave ----
__global__ __launch_bounds__(256) void k_rowalloc(const int* __restrict__ cnt, int* __restrict__ row_start,
                                                  int* __restrict__ cursor, int* __restrict__ gcur, int n) {
  int i = blockIdx.x * 256 + threadIdx.x;
  int lane = threadIdx.x & 63;
  int c = (i < n) ? cnt[i] : 0;
  int s = c;
  #pragma unroll
  for (int d = 1; d < 64; d <<= 1) {
    int t = __shfl_up(s, d, 64);
    if (lane >= d) s += t;
  }
  int total = __shfl(s, 63, 64);
  int base = 0;
  if (lane == 63) base = atomicAdd(gcur, total);
  base = __shfl(base, 63, 64);
  int start = base + s - c;
  if (i < n) {
    row_start[i] = start;
    cursor[i] = start;
  }
}

__global__ __launch_bounds__(256) void k_fill(const int* __restrict__ src, const int* __restrict__ dst,
                                              int* __restrict__ cursor, int* __restrict__ col, int E) {
  int e = blockIdx.x * 256 + threadIdx.x;
  if (e < E) {
    int pos = atomicAdd(&cursor[dst[e]], 1);
    col[pos] = src[e];
  }
}

// ---- gemm0: hs[row] = ns[row] * (feats[row] @ W0), 256->64 ----
#define G0PAD 36
__global__ __launch_bounds__(256) void k_gemm0(const float* __restrict__ feats, const float* __restrict__ ns,
                                               const float* __restrict__ W0, float* __restrict__ hs, int nrows) {
  __shared__ float sA[64 * G0PAD];
  __shared__ float sW[32 * 64];
  const int tid = threadIdx.x;
  const int row0 = blockIdx.x * 64;
  const int tr4 = (tid >> 4) * 4;
  const int tc4 = (tid & 15) * 4;
  const int sr = tid >> 3;
  const int sc = (tid & 7) * 4;
  const int wk = tid >> 3;
  float4 acc0 = {0,0,0,0}, acc1 = {0,0,0,0}, acc2 = {0,0,0,0}, acc3 = {0,0,0,0};
  const float4 z4 = {0,0,0,0};

  for (int kb = 0; kb < FIN; kb += 32) {
    __syncthreads();
    {
      int r1 = row0 + sr, r2 = row0 + sr + 32;
      float4 v1 = (r1 < nrows) ? *(const float4*)&feats[(size_t)r1 * FIN + kb + sc] : z4;
      float4 v2 = (r2 < nrows) ? *(const float4*)&feats[(size_t)r2 * FIN + kb + sc] : z4;
      *(float4*)&sA[sr * G0PAD + sc] = v1;
      *(float4*)&sA[(sr + 32) * G0PAD + sc] = v2;
      *(float4*)&sW[wk * 64 + sc]      = *(const float4*)&W0[(size_t)(kb + wk) * HID + sc];
      *(float4*)&sW[wk * 64 + sc + 32] = *(const float4*)&W0[(size_t)(kb + wk) * HID + sc + 32];
    }
    __syncthreads();
    #pragma unroll
    for (int kc = 0; kc < 32; kc += 4) {
      float4 a0 = *(const float4*)&sA[(tr4 + 0) * G0PAD + kc];
      float4 a1 = *(const float4*)&sA[(tr4 + 1) * G0PAD + kc];
      float4 a2 = *(const float4*)&sA[(tr4 + 2) * G0PAD + kc];
      float4 a3 = *(const float4*)&sA[(tr4 + 3) * G0PAD + kc];
      #define G0STEP(KK, C) { \
        float4 wv = *(const float4*)&sW[(kc + KK) * 64 + tc4]; \
        FMA4(acc0, a0.C, wv); FMA4(acc1, a1.C, wv); FMA4(acc2, a2.C, wv); FMA4(acc3, a3.C, wv); }
      G0STEP(0, x) G0STEP(1, y) G0STEP(2, z) G0STEP(3, w)
      #undef G0STEP
    }
  }
  #pragma unroll
  for (int r = 0; r < 4; ++r) {
    int row = row0 + tr4 + r;
    if (row < nrows) {
      float s = ns[row];
      float4 o = (r == 0) ? acc0 : (r == 1) ? acc1 : (r == 2) ? acc2 : acc3;
      o.x *= s; o.y *= s; o.z *= s; o.w *= s;
      *(float4*)&hs[(size_t)row * HID + tc4] = o;
    }
  }
}

// ---- dual GEMM: hs = ns*(h@W); proj += h@Wb.  64 rows/block, K=64 whole. ----
// launch_bounds(256,4) + unroll 2: keep VGPR <=128 (R4 post-mortem: spill -> 1.7GB traffic).
#define GDPAD 68
template<bool HASW>
__global__ __launch_bounds__(256, 4) void k_gemm_dual(const float* __restrict__ h, const float* __restrict__ ns,
                                                      const float* __restrict__ W, const float* __restrict__ Wb,
                                                      float* __restrict__ hs, float* __restrict__ proj, int nrows) {
  __shared__ float sA[64 * GDPAD];
  __shared__ float sW[64 * 64];
  __shared__ float sWb[64 * 64];
  const int tid = threadIdx.x;
  const int row0 = blockIdx.x * 64;
  const int tr4 = (tid >> 4) * 4;
  const int tc4 = (tid & 15) * 4;
  const int sr = tid >> 2;
  const int scb = (tid & 3) * 16;
  const float4 z4 = {0,0,0,0};

  {
    int gr = row0 + sr;
    #pragma unroll
    for (int o = 0; o < 16; o += 4) {
      float4 v = (gr < nrows) ? *(const float4*)&h[(size_t)gr * HID + scb + o] : z4;
      *(float4*)&sA[sr * GDPAD + scb + o] = v;
      if (HASW) *(float4*)&sW[sr * 64 + scb + o] = *(const float4*)&W[(size_t)sr * HID + scb + o];
      *(float4*)&sWb[sr * 64 + scb + o] = *(const float4*)&Wb[(size_t)sr * HID + scb + o];
    }
  }
  __syncthreads();

  float4 aw0 = {0,0,0,0}, aw1 = {0,0,0,0}, aw2 = {0,0,0,0}, aw3 = {0,0,0,0};
  float4 ab0 = {0,0,0,0}, ab1 = {0,0,0,0}, ab2 = {0,0,0,0}, ab3 = {0,0,0,0};
  #pragma unroll 2
  for (int kc = 0; kc < 64; kc += 4) {
    float4 a0 = *(const float4*)&sA[(tr4 + 0) * GDPAD + kc];
    float4 a1 = *(const float4*)&sA[(tr4 + 1) * GDPAD + kc];
    float4 a2 = *(const float4*)&sA[(tr4 + 2) * GDPAD + kc];
    float4 a3 = *(const float4*)&sA[(tr4 + 3) * GDPAD + kc];
    #define GDSTEP(KK, C) { \
      if (HASW) { \
        float4 wv = *(const float4*)&sW[(kc + KK) * 64 + tc4]; \
        FMA4(aw0, a0.C, wv); FMA4(aw1, a1.C, wv); FMA4(aw2, a2.C, wv); FMA4(aw3, a3.C, wv); } \
      { float4 wbv = *(const float4*)&sWb[(kc + KK) * 64 + tc4]; \
        FMA4(ab0, a0.C, wbv); FMA4(ab1, a1.C, wbv); FMA4(ab2, a2.C, wbv); FMA4(ab3, a3.C, wbv); } }
    GDSTEP(0, x) GDSTEP(1, y) GDSTEP(2, z) GDSTEP(3, w)
    #undef GDSTEP
  }

  #pragma unroll
  for (int r = 0; r < 4; ++r) {
    int row = row0 + tr4 + r;
    if (row < nrows) {
      if (HASW) {
        float s = ns[row];
        float4 o = (r == 0) ? aw0 : (r == 1) ? aw1 : (r == 2) ? aw2 : aw3;
        o.x *= s; o.y *= s; o.z *= s; o.w *= s;
        *(float4*)&hs[(size_t)row * HID + tc4] = o;
      }
      float4 ob = (r == 0) ? ab0 : (r == 1) ? ab1 : (r == 2) ? ab2 : ab3;
      float4 p = *(const float4*)&proj[(size_t)row * HID + tc4];
      p.x += ob.x; p.y += ob.y; p.z += ob.z; p.w += ob.w;
      *(float4*)&proj[(size_t)row * HID + tc4] = p;
    }
  }
}

// ---- sliced gather-sum: slice-major grid so the active 3.2MB x-slice is L2-resident per XCD ----
// grid.x = NSLICE * nb, nb = ceil(N/4); 4 waves/block, wave per node.
// wave: 8 edge-groups x 8 lanes x 4B; reduce over groups via shfl_xor 8/16/32.
template<bool RELU>
__global__ __launch_bounds__(256) void k_gather8(const int* __restrict__ row_start, const int* __restrict__ cnt,
                                                 const int* __restrict__ col, const float* __restrict__ x,
                                                 const float* __restrict__ nd, const float* __restrict__ b,
                                                 float* __restrict__ y, int n, int nb) {
  int bid = blockIdx.x;
  int slice = bid / nb;
  int node = (bid - slice * nb) * 4 + (threadIdx.x >> 6);
  if (node >= n) return;
  int lane = threadIdx.x & 63;
  int g = lane >> 3;          // edge group 0..7
  int fl = lane & 7;          // feature within slice
  int f = slice * 8 + fl;
  int j0 = row_start[node];
  int jend = j0 + cnt[node];
  float acc = 0.f;
  for (int j = j0 + g; j < jend; j += 8) {
    int s = col[j];
    acc += x[(size_t)s * HID + f];
  }
  acc += __shfl_xor(acc, 8, 64);
  acc += __shfl_xor(acc, 16, 64);
  acc += __shfl_xor(acc, 32, 64);
  if (g == 0) {
    float v;
    if (RELU) v = fmaxf(acc * nd[node] + b[f], 0.f);
    else      v = acc + b[f];
    y[(size_t)node * HID + f] = v;
  }
}

extern "C" void kernel_launch(void* const* d_in, const int* in_sizes, int n_in,
                              void* d_out, int out_size, void* d_ws, size_t ws_size,
                              hipStream_t stream) {
  const float* feats = (const float*)d_in[0];
  const int* src = (const int*)d_in[1];
  const int* dst = (const int*)d_in[2];
  const float* W[NLAYERS]    = {(const float*)d_in[3], (const float*)d_in[5], (const float*)d_in[7],
                                (const float*)d_in[9], (const float*)d_in[11]};
  const float* bias[NLAYERS] = {(const float*)d_in[4], (const float*)d_in[6], (const float*)d_in[8],
                                (const float*)d_in[10], (const float*)d_in[12]};
  const float* Wout = (const float*)d_in[13];
  const float* bout = (const float*)d_in[14];
  float* out = (float*)d_out;

  const int N = in_sizes[0] / FIN;
  const int E = in_sizes[1];
  const size_t Np = (size_t)((N + 63) / 64) * 64;
  const size_t Ep = (size_t)((E + 63) / 64) * 64;

  char* w = (char*)d_ws;
  int* cnt_s     = (int*)w;            w += Np * 4;
  int* cnt_d     = (int*)w;            w += Np * 4;
  int* row_start = (int*)w;            w += Np * 4;
  int* cursor    = (int*)w;            w += Np * 4;
  int* gcur      = (int*)w;            w += 64 * 4;
  int* col       = (int*)w;            w += Ep * 4;
  float* norm_s  = (float*)w;          w += Np * 4;
  float* norm_d  = (float*)w;          w += Np * 4;
  float* h       = (float*)w;          w += Np * HID * 4;
  float* hsbuf   = (float*)w;          w += Np * HID * 4;
  float* proj    = (float*)w;          w += Np * HID * 4;

  (void)hipMemsetAsync(cnt_s, 0, 2 * Np * sizeof(int), stream);
  (void)hipMemsetAsync(gcur, 0, sizeof(int), stream);
  (void)hipMemsetAsync(proj, 0, (size_t)N * HID * sizeof(float), stream);

  k_deg_i<<<(E + 255) / 256, 256, 0, stream>>>(src, dst, cnt_s, cnt_d, E);
  k_norm<<<(int)((2 * Np + 255) / 256), 256, 0, stream>>>(cnt_s, norm_s, (int)(2 * Np));
  k_rowalloc<<<(N + 255) / 256, 256, 0, stream>>>(cnt_d, row_start, cursor, gcur, N);
  k_fill<<<(E + 255) / 256, 256, 0, stream>>>(src, dst, cursor, col, E);

  const int GEMMB = (N + 63) / 64;
  k_gemm0<<<GEMMB, 256, 0, stream>>>(feats, norm_s, W[0], hsbuf, N);

  const int NB = (N + 3) / 4;
  const int GGRID = NSLICE * NB;
  for (int i = 0; i < NLAYERS; ++i) {
    k_gather8<true><<<GGRID, 256, 0, stream>>>(row_start, cnt_d, col, hsbuf, norm_d, bias[i], h, N, NB);
    if (i < NLAYERS - 1) {
      k_gemm_dual<true><<<GEMMB, 256, 0, stream>>>(h, norm_s, W[i + 1], Wout + (size_t)i * HID * HID,
                                                   hsbuf, proj, N);
    } else {
      k_gemm_dual<false><<<GEMMB, 256, 0, stream>>>(h, norm_s, nullptr, Wout + (size_t)i * HID * HID,
                                                    hsbuf, proj, N);
    }
  }
  k_gather8<false><<<GGRID, 256, 0, stream>>>(row_start, cnt_d, col, proj, nullptr, bout, out, N, NB);
}

// Round 8
// 848.776 us; speedup vs baseline: 2.8033x; 2.8033x over previous
//
#include <hip/hip_runtime.h>

#define FIN 256
#define HID 64
#define NLAYERS 5

#define FMA4(ACC, S, V) { float _s = (S); ACC.x += _s*(V).x; ACC.y += _s*(V).y; ACC.z += _s*(V).z; ACC.w += _s*(V).w; }

__device__ inline unsigned short f2bf(float f) {            // round-to-nearest-even
  unsigned u = __float_as_uint(f);
  u += 0x7FFF + ((u >> 16) & 1);
  return (unsigned short)(u >> 16);
}
__device__ inline float bf2f(unsigned short s) { return __uint_as_float(((unsigned)s) << 16); }

// ---- degree histogram (int) ----
__global__ __launch_bounds__(256) void k_deg_i(const int* __restrict__ src, const int* __restrict__ dst,
                                               int* __restrict__ cs, int* __restrict__ cd, int E) {
  int i = blockIdx.x * 256 + threadIdx.x;
  if (i < E) {
    atomicAdd(&cs[src[i]], 1);
    atomicAdd(&cd[dst[i]], 1);
  }
}

__global__ __launch_bounds__(256) void k_norm(const int* __restrict__ cnt, float* __restrict__ nrm, int n) {
  int i = blockIdx.x * 256 + threadIdx.x;
  if (i < n) nrm[i] = rsqrtf(fmaxf((float)cnt[i], 1.0f));
}

// ---- CSR row allocation: wave scan + one atomic per wave ----
__global__ __launch_bounds__(256) void k_rowalloc(const int* __restrict__ cnt, int* __restrict__ row_start,
                                                  int* __restrict__ cursor, int* __restrict__ gcur, int n) {
  int i = blockIdx.x * 256 + threadIdx.x;
  int lane = threadIdx.x & 63;
  int c = (i < n) ? cnt[i] : 0;
  int s = c;
  #pragma unroll
  for (int d = 1; d < 64; d <<= 1) {
    int t = __shfl_up(s, d, 64);
    if (lane >= d) s += t;
  }
  int total = __shfl(s, 63, 64);
  int base = 0;
  if (lane == 63) base = atomicAdd(gcur, total);
  base = __shfl(base, 63, 64);
  int start = base + s - c;
  if (i < n) {
    row_start[i] = start;
    cursor[i] = start;
  }
}

__global__ __launch_bounds__(256) void k_fill(const int* __restrict__ src, const int* __restrict__ dst,
                                              int* __restrict__ cursor, int* __restrict__ col, int E) {
  int e = blockIdx.x * 256 + threadIdx.x;
  if (e < E) {
    int pos = atomicAdd(&cursor[dst[e]], 1);
    col[pos] = src[e];
  }
}

// ---- gemm0: hs[row] = bf16( ns[row] * (feats[row] @ W0) ), 256->64 ----
#define G0PAD 36
__global__ __launch_bounds__(256) void k_gemm0(const float* __restrict__ feats, const float* __restrict__ ns,
                                               const float* __restrict__ W0, unsigned short* __restrict__ hs,
                                               int nrows) {
  __shared__ float sA[64 * G0PAD];
  __shared__ float sW[32 * 64];
  const int tid = threadIdx.x;
  const int row0 = blockIdx.x * 64;
  const int tr4 = (tid >> 4) * 4;
  const int tc4 = (tid & 15) * 4;
  const int sr = tid >> 3;
  const int sc = (tid & 7) * 4;
  const int wk = tid >> 3;
  float4 acc0 = {0,0,0,0}, acc1 = {0,0,0,0}, acc2 = {0,0,0,0}, acc3 = {0,0,0,0};
  const float4 z4 = {0,0,0,0};

  for (int kb = 0; kb < FIN; kb += 32) {
    __syncthreads();
    {
      int r1 = row0 + sr, r2 = row0 + sr + 32;
      float4 v1 = (r1 < nrows) ? *(const float4*)&feats[(size_t)r1 * FIN + kb + sc] : z4;
      float4 v2 = (r2 < nrows) ? *(const float4*)&feats[(size_t)r2 * FIN + kb + sc] : z4;
      *(float4*)&sA[sr * G0PAD + sc] = v1;
      *(float4*)&sA[(sr + 32) * G0PAD + sc] = v2;
      *(float4*)&sW[wk * 64 + sc]      = *(const float4*)&W0[(size_t)(kb + wk) * HID + sc];
      *(float4*)&sW[wk * 64 + sc + 32] = *(const float4*)&W0[(size_t)(kb + wk) * HID + sc + 32];
    }
    __syncthreads();
    #pragma unroll
    for (int kc = 0; kc < 32; kc += 4) {
      float4 a0 = *(const float4*)&sA[(tr4 + 0) * G0PAD + kc];
      float4 a1 = *(const float4*)&sA[(tr4 + 1) * G0PAD + kc];
      float4 a2 = *(const float4*)&sA[(tr4 + 2) * G0PAD + kc];
      float4 a3 = *(const float4*)&sA[(tr4 + 3) * G0PAD + kc];
      #define G0STEP(KK, C) { \
        float4 wv = *(const float4*)&sW[(kc + KK) * 64 + tc4]; \
        FMA4(acc0, a0.C, wv); FMA4(acc1, a1.C, wv); FMA4(acc2, a2.C, wv); FMA4(acc3, a3.C, wv); }
      G0STEP(0, x) G0STEP(1, y) G0STEP(2, z) G0STEP(3, w)
      #undef G0STEP
    }
  }
  #pragma unroll
  for (int r = 0; r < 4; ++r) {
    int row = row0 + tr4 + r;
    if (row < nrows) {
      float s = ns[row];
      float4 o = (r == 0) ? acc0 : (r == 1) ? acc1 : (r == 2) ? acc2 : acc3;
      ushort4 p;
      p.x = f2bf(o.x * s); p.y = f2bf(o.y * s); p.z = f2bf(o.z * s); p.w = f2bf(o.w * s);
      *(ushort4*)&hs[(size_t)row * HID + tc4] = p;
    }
  }
}

// ---- dual GEMM: hs(bf16) = ns*(h@W); proj(f32) += h@Wb.  64 rows/block, K=64 whole. ----
// launch_bounds(256,4) + unroll 2: keep VGPR <=128 (R4 post-mortem: spill -> 1.7GB traffic).
#define GDPAD 68
template<bool HASW>
__global__ __launch_bounds__(256, 4) void k_gemm_dual(const float* __restrict__ h, const float* __restrict__ ns,
                                                      const float* __restrict__ W, const float* __restrict__ Wb,
                                                      unsigned short* __restrict__ hs, float* __restrict__ proj,
                                                      int nrows) {
  __shared__ float sA[64 * GDPAD];
  __shared__ float sW[64 * 64];
  __shared__ float sWb[64 * 64];
  const int tid = threadIdx.x;
  const int row0 = blockIdx.x * 64;
  const int tr4 = (tid >> 4) * 4;
  const int tc4 = (tid & 15) * 4;
  const int sr = tid >> 2;
  const int scb = (tid & 3) * 16;
  const float4 z4 = {0,0,0,0};

  {
    int gr = row0 + sr;
    #pragma unroll
    for (int o = 0; o < 16; o += 4) {
      float4 v = (gr < nrows) ? *(const float4*)&h[(size_t)gr * HID + scb + o] : z4;
      *(float4*)&sA[sr * GDPAD + scb + o] = v;
      if (HASW) *(float4*)&sW[sr * 64 + scb + o] = *(const float4*)&W[(size_t)sr * HID + scb + o];
      *(float4*)&sWb[sr * 64 + scb + o] = *(const float4*)&Wb[(size_t)sr * HID + scb + o];
    }
  }
  __syncthreads();

  float4 aw0 = {0,0,0,0}, aw1 = {0,0,0,0}, aw2 = {0,0,0,0}, aw3 = {0,0,0,0};
  float4 ab0 = {0,0,0,0}, ab1 = {0,0,0,0}, ab2 = {0,0,0,0}, ab3 = {0,0,0,0};
  #pragma unroll 2
  for (int kc = 0; kc < 64; kc += 4) {
    float4 a0 = *(const float4*)&sA[(tr4 + 0) * GDPAD + kc];
    float4 a1 = *(const float4*)&sA[(tr4 + 1) * GDPAD + kc];
    float4 a2 = *(const float4*)&sA[(tr4 + 2) * GDPAD + kc];
    float4 a3 = *(const float4*)&sA[(tr4 + 3) * GDPAD + kc];
    #define GDSTEP(KK, C) { \
      if (HASW) { \
        float4 wv = *(const float4*)&sW[(kc + KK) * 64 + tc4]; \
        FMA4(aw0, a0.C, wv); FMA4(aw1, a1.C, wv); FMA4(aw2, a2.C, wv); FMA4(aw3, a3.C, wv); } \
      { float4 wbv = *(const float4*)&sWb[(kc + KK) * 64 + tc4]; \
        FMA4(ab0, a0.C, wbv); FMA4(ab1, a1.C, wbv); FMA4(ab2, a2.C, wbv); FMA4(ab3, a3.C, wbv); } }
    GDSTEP(0, x) GDSTEP(1, y) GDSTEP(2, z) GDSTEP(3, w)
    #undef GDSTEP
  }

  #pragma unroll
  for (int r = 0; r < 4; ++r) {
    int row = row0 + tr4 + r;
    if (row < nrows) {
      if (HASW) {
        float s = ns[row];
        float4 o = (r == 0) ? aw0 : (r == 1) ? aw1 : (r == 2) ? aw2 : aw3;
        ushort4 pk;
        pk.x = f2bf(o.x * s); pk.y = f2bf(o.y * s); pk.z = f2bf(o.z * s); pk.w = f2bf(o.w * s);
        *(ushort4*)&hs[(size_t)row * HID + tc4] = pk;
      }
      float4 ob = (r == 0) ? ab0 : (r == 1) ? ab1 : (r == 2) ? ab2 : ab3;
      float4 p = *(const float4*)&proj[(size_t)row * HID + tc4];
      p.x += ob.x; p.y += ob.y; p.z += ob.z; p.w += ob.w;
      *(float4*)&proj[(size_t)row * HID + tc4] = p;
    }
  }
}

// ---- layer gather-sum over bf16 table: wave per node, 4 edge-groups x 16 lanes x (4 bf16 = 8B) ----
__global__ __launch_bounds__(256) void k_gather_bf(const int* __restrict__ row_start, const int* __restrict__ cnt,
                                                   const int* __restrict__ col, const unsigned short* __restrict__ x,
                                                   const float* __restrict__ nd, const float* __restrict__ b,
                                                   float* __restrict__ y, int n) {
  int node = blockIdx.x * 4 + (threadIdx.x >> 6);
  if (node >= n) return;
  int lane = threadIdx.x & 63;
  int g = lane >> 4;
  int fl = (lane & 15) * 4;
  int j0 = row_start[node];
  int jend = j0 + cnt[node];
  float4 acc = {0,0,0,0};
  for (int j = j0 + g; j < jend; j += 4) {
    int s = col[j];
    ushort4 u = *(const ushort4*)&x[(size_t)s * HID + fl];
    acc.x += bf2f(u.x); acc.y += bf2f(u.y); acc.z += bf2f(u.z); acc.w += bf2f(u.w);
  }
  #pragma unroll
  for (int m = 16; m <= 32; m <<= 1) {
    acc.x += __shfl_xor(acc.x, m, 64);
    acc.y += __shfl_xor(acc.y, m, 64);
    acc.z += __shfl_xor(acc.z, m, 64);
    acc.w += __shfl_xor(acc.w, m, 64);
  }
  if (g == 0) {
    float s = nd[node];
    float4 bb = *(const float4*)&b[fl];
    float4 o;
    o.x = fmaxf(acc.x * s + bb.x, 0.f);
    o.y = fmaxf(acc.y * s + bb.y, 0.f);
    o.z = fmaxf(acc.z * s + bb.z, 0.f);
    o.w = fmaxf(acc.w * s + bb.w, 0.f);
    *(float4*)&y[(size_t)node * HID + fl] = o;
  }
}

// ---- final gather-sum over fp32 proj: wave per node, + bout ----
__global__ __launch_bounds__(256) void k_gather_f32(const int* __restrict__ row_start, const int* __restrict__ cnt,
                                                    const int* __restrict__ col, const float* __restrict__ x,
                                                    const float* __restrict__ bout, float* __restrict__ y, int n) {
  int node = blockIdx.x * 4 + (threadIdx.x >> 6);
  if (node >= n) return;
  int lane = threadIdx.x & 63;
  int g = lane >> 4;
  int fl = (lane & 15) * 4;
  int j0 = row_start[node];
  int jend = j0 + cnt[node];
  float4 acc = {0,0,0,0};
  for (int j = j0 + g; j < jend; j += 4) {
    int s = col[j];
    float4 v = *(const float4*)&x[(size_t)s * HID + fl];
    acc.x += v.x; acc.y += v.y; acc.z += v.z; acc.w += v.w;
  }
  #pragma unroll
  for (int m = 16; m <= 32; m <<= 1) {
    acc.x += __shfl_xor(acc.x, m, 64);
    acc.y += __shfl_xor(acc.y, m, 64);
    acc.z += __shfl_xor(acc.z, m, 64);
    acc.w += __shfl_xor(acc.w, m, 64);
  }
  if (g == 0) {
    float4 bb = *(const float4*)&bout[fl];
    float4 o = {acc.x + bb.x, acc.y + bb.y, acc.z + bb.z, acc.w + bb.w};
    *(float4*)&y[(size_t)node * HID + fl] = o;
  }
}

extern "C" void kernel_launch(void* const* d_in, const int* in_sizes, int n_in,
                              void* d_out, int out_size, void* d_ws, size_t ws_size,
                              hipStream_t stream) {
  const float* feats = (const float*)d_in[0];
  const int* src = (const int*)d_in[1];
  const int* dst = (const int*)d_in[2];
  const float* W[NLAYERS]    = {(const float*)d_in[3], (const float*)d_in[5], (const float*)d_in[7],
                                (const float*)d_in[9], (const float*)d_in[11]};
  const float* bias[NLAYERS] = {(const float*)d_in[4], (const float*)d_in[6], (const float*)d_in[8],
                                (const float*)d_in[10], (const float*)d_in[12]};
  const float* Wout = (const float*)d_in[13];
  const float* bout = (const float*)d_in[14];
  float* out = (float*)d_out;

  const int N = in_sizes[0] / FIN;
  const int E = in_sizes[1];
  const size_t Np = (size_t)((N + 63) / 64) * 64;
  const size_t Ep = (size_t)((E + 63) / 64) * 64;

  char* w = (char*)d_ws;
  int* cnt_s     = (int*)w;            w += Np * 4;
  int* cnt_d     = (int*)w;            w += Np * 4;
  int* row_start = (int*)w;            w += Np * 4;
  int* cursor    = (int*)w;            w += Np * 4;
  int* gcur      = (int*)w;            w += 64 * 4;
  int* col       = (int*)w;            w += Ep * 4;
  float* norm_s  = (float*)w;          w += Np * 4;
  float* norm_d  = (float*)w;          w += Np * 4;
  float* h       = (float*)w;          w += Np * HID * 4;
  float* proj    = (float*)w;          w += Np * HID * 4;
  unsigned short* hsbuf = (unsigned short*)w;  w += Np * HID * 2;

  (void)hipMemsetAsync(cnt_s, 0, 2 * Np * sizeof(int), stream);
  (void)hipMemsetAsync(gcur, 0, sizeof(int), stream);
  (void)hipMemsetAsync(proj, 0, (size_t)N * HID * sizeof(float), stream);

  k_deg_i<<<(E + 255) / 256, 256, 0, stream>>>(src, dst, cnt_s, cnt_d, E);
  k_norm<<<(int)((2 * Np + 255) / 256), 256, 0, stream>>>(cnt_s, norm_s, (int)(2 * Np));
  k_rowalloc<<<(N + 255) / 256, 256, 0, stream>>>(cnt_d, row_start, cursor, gcur, N);
  k_fill<<<(E + 255) / 256, 256, 0, stream>>>(src, dst, cursor, col, E);

  const int GEMMB = (N + 63) / 64;
  k_gemm0<<<GEMMB, 256, 0, stream>>>(feats, norm_s, W[0], hsbuf, N);

  const int GB = (N + 3) / 4;
  for (int i = 0; i < NLAYERS; ++i) {
    k_gather_bf<<<GB, 256, 0, stream>>>(row_start, cnt_d, col, hsbuf, norm_d, bias[i], h, N);
    if (i < NLAYERS - 1) {
      k_gemm_dual<true><<<GEMMB, 256, 0, stream>>>(h, norm_s, W[i + 1], Wout + (size_t)i * HID * HID,
                                                   hsbuf, proj, N);
    } else {
      k_gemm_dual<false><<<GEMMB, 256, 0, stream>>>(h, norm_s, nullptr, Wout + (size_t)i * HID * HID,
                                                    nullptr, proj, N);
    }
  }
  k_gather_f32<<<GB, 256, 0, stream>>>(row_start, cnt_d, col, proj, bout, out, N);
}

// Round 9
// 761.205 us; speedup vs baseline: 3.1258x; 1.1150x over previous
//
#include <hip/hip_runtime.h>

#define FIN 256
#define HID 64
#define NLAYERS 5

#define FMA4(ACC, S, V) { float _s = (S); ACC.x += _s*(V).x; ACC.y += _s*(V).y; ACC.z += _s*(V).z; ACC.w += _s*(V).w; }

__device__ inline unsigned short f2bf(float f) {            // round-to-nearest-even
  unsigned u = __float_as_uint(f);
  u += 0x7FFF + ((u >> 16) & 1);
  return (unsigned short)(u >> 16);
}
__device__ inline float bf2f(unsigned short s) { return __uint_as_float(((unsigned)s) << 16); }

// ---- count: src histogram + dst histogram with returned rank ----
__global__ __launch_bounds__(256) void k_count(const int* __restrict__ src, const int* __restrict__ dst,
                                               int* __restrict__ cs, int* __restrict__ cd,
                                               int* __restrict__ rank, int E) {
  int i = blockIdx.x * 256 + threadIdx.x;
  if (i < E) {
    atomicAdd(&cs[src[i]], 1);
    rank[i] = atomicAdd(&cd[dst[i]], 1);
  }
}

__global__ __launch_bounds__(256) void k_norm(const int* __restrict__ cnt, float* __restrict__ nrm, int n) {
  int i = blockIdx.x * 256 + threadIdx.x;
  if (i < n) nrm[i] = rsqrtf(fmaxf((float)cnt[i], 1.0f));
}

// ---- CSR row allocation: wave scan + one atomic per wave ----
__global__ __launch_bounds__(256) void k_rowalloc(const int* __restrict__ cnt, int* __restrict__ row_start,
                                                  int* __restrict__ gcur, int n) {
  int i = blockIdx.x * 256 + threadIdx.x;
  int lane = threadIdx.x & 63;
  int c = (i < n) ? cnt[i] : 0;
  int s = c;
  #pragma unroll
  for (int d = 1; d < 64; d <<= 1) {
    int t = __shfl_up(s, d, 64);
    if (lane >= d) s += t;
  }
  int total = __shfl(s, 63, 64);
  int base = 0;
  if (lane == 63) base = atomicAdd(gcur, total);
  base = __shfl(base, 63, 64);
  int start = base + s - c;
  if (i < n) row_start[i] = start;
}

// ---- place: atomic-free CSR fill using precomputed ranks ----
__global__ __launch_bounds__(256) void k_place(const int* __restrict__ src, const int* __restrict__ dst,
                                               const int* __restrict__ rank, const int* __restrict__ row_start,
                                               int* __restrict__ col, int E) {
  int e = blockIdx.x * 256 + threadIdx.x;
  if (e < E) col[row_start[dst[e]] + rank[e]] = src[e];
}

// ---- gemm0: hs[row] = bf16( ns[row] * (feats[row] @ W0) ), 256->64 ----
#define G0PAD 36
__global__ __launch_bounds__(256) void k_gemm0(const float* __restrict__ feats, const float* __restrict__ ns,
                                               const float* __restrict__ W0, unsigned short* __restrict__ hs,
                                               int nrows) {
  __shared__ float sA[64 * G0PAD];
  __shared__ float sW[32 * 64];
  const int tid = threadIdx.x;
  const int row0 = blockIdx.x * 64;
  const int tr4 = (tid >> 4) * 4;
  const int tc4 = (tid & 15) * 4;
  const int sr = tid >> 3;
  const int sc = (tid & 7) * 4;
  const int wk = tid >> 3;
  float4 acc0 = {0,0,0,0}, acc1 = {0,0,0,0}, acc2 = {0,0,0,0}, acc3 = {0,0,0,0};
  const float4 z4 = {0,0,0,0};

  for (int kb = 0; kb < FIN; kb += 32) {
    __syncthreads();
    {
      int r1 = row0 + sr, r2 = row0 + sr + 32;
      float4 v1 = (r1 < nrows) ? *(const float4*)&feats[(size_t)r1 * FIN + kb + sc] : z4;
      float4 v2 = (r2 < nrows) ? *(const float4*)&feats[(size_t)r2 * FIN + kb + sc] : z4;
      *(float4*)&sA[sr * G0PAD + sc] = v1;
      *(float4*)&sA[(sr + 32) * G0PAD + sc] = v2;
      *(float4*)&sW[wk * 64 + sc]      = *(const float4*)&W0[(size_t)(kb + wk) * HID + sc];
      *(float4*)&sW[wk * 64 + sc + 32] = *(const float4*)&W0[(size_t)(kb + wk) * HID + sc + 32];
    }
    __syncthreads();
    #pragma unroll
    for (int kc = 0; kc < 32; kc += 4) {
      float4 a0 = *(const float4*)&sA[(tr4 + 0) * G0PAD + kc];
      float4 a1 = *(const float4*)&sA[(tr4 + 1) * G0PAD + kc];
      float4 a2 = *(const float4*)&sA[(tr4 + 2) * G0PAD + kc];
      float4 a3 = *(const float4*)&sA[(tr4 + 3) * G0PAD + kc];
      #define G0STEP(KK, C) { \
        float4 wv = *(const float4*)&sW[(kc + KK) * 64 + tc4]; \
        FMA4(acc0, a0.C, wv); FMA4(acc1, a1.C, wv); FMA4(acc2, a2.C, wv); FMA4(acc3, a3.C, wv); }
      G0STEP(0, x) G0STEP(1, y) G0STEP(2, z) G0STEP(3, w)
      #undef G0STEP
    }
  }
  #pragma unroll
  for (int r = 0; r < 4; ++r) {
    int row = row0 + tr4 + r;
    if (row < nrows) {
      float s = ns[row];
      float4 o = (r == 0) ? acc0 : (r == 1) ? acc1 : (r == 2) ? acc2 : acc3;
      ushort4 p;
      p.x = f2bf(o.x * s); p.y = f2bf(o.y * s); p.z = f2bf(o.z * s); p.w = f2bf(o.w * s);
      *(ushort4*)&hs[(size_t)row * HID + tc4] = p;
    }
  }
}

// ---- dual GEMM.  HASW: hs(bf16) = ns*(h@W), proj(f32) += h@Wb.
//      !HASW (last layer): hs(bf16) = bf16(proj + h@Wb)  [final JK table], proj not written.
// launch_bounds(256,4) + unroll 2: keep VGPR <=128 (R4 post-mortem: spill -> 1.7GB traffic).
#define GDPAD 68
template<bool HASW>
__global__ __launch_bounds__(256, 4) void k_gemm_dual(const float* __restrict__ h, const float* __restrict__ ns,
                                                      const float* __restrict__ W, const float* __restrict__ Wb,
                                                      unsigned short* __restrict__ hs, float* __restrict__ proj,
                                                      int nrows) {
  __shared__ float sA[64 * GDPAD];
  __shared__ float sW[64 * 64];
  __shared__ float sWb[64 * 64];
  const int tid = threadIdx.x;
  const int row0 = blockIdx.x * 64;
  const int tr4 = (tid >> 4) * 4;
  const int tc4 = (tid & 15) * 4;
  const int sr = tid >> 2;
  const int scb = (tid & 3) * 16;
  const float4 z4 = {0,0,0,0};

  {
    int gr = row0 + sr;
    #pragma unroll
    for (int o = 0; o < 16; o += 4) {
      float4 v = (gr < nrows) ? *(const float4*)&h[(size_t)gr * HID + scb + o] : z4;
      *(float4*)&sA[sr * GDPAD + scb + o] = v;
      if (HASW) *(float4*)&sW[sr * 64 + scb + o] = *(const float4*)&W[(size_t)sr * HID + scb + o];
      *(float4*)&sWb[sr * 64 + scb + o] = *(const float4*)&Wb[(size_t)sr * HID + scb + o];
    }
  }
  __syncthreads();

  float4 aw0 = {0,0,0,0}, aw1 = {0,0,0,0}, aw2 = {0,0,0,0}, aw3 = {0,0,0,0};
  float4 ab0 = {0,0,0,0}, ab1 = {0,0,0,0}, ab2 = {0,0,0,0}, ab3 = {0,0,0,0};
  #pragma unroll 2
  for (int kc = 0; kc < 64; kc += 4) {
    float4 a0 = *(const float4*)&sA[(tr4 + 0) * GDPAD + kc];
    float4 a1 = *(const float4*)&sA[(tr4 + 1) * GDPAD + kc];
    float4 a2 = *(const float4*)&sA[(tr4 + 2) * GDPAD + kc];
    float4 a3 = *(const float4*)&sA[(tr4 + 3) * GDPAD + kc];
    #define GDSTEP(KK, C) { \
      if (HASW) { \
        float4 wv = *(const float4*)&sW[(kc + KK) * 64 + tc4]; \
        FMA4(aw0, a0.C, wv); FMA4(aw1, a1.C, wv); FMA4(aw2, a2.C, wv); FMA4(aw3, a3.C, wv); } \
      { float4 wbv = *(const float4*)&sWb[(kc + KK) * 64 + tc4]; \
        FMA4(ab0, a0.C, wbv); FMA4(ab1, a1.C, wbv); FMA4(ab2, a2.C, wbv); FMA4(ab3, a3.C, wbv); } }
    GDSTEP(0, x) GDSTEP(1, y) GDSTEP(2, z) GDSTEP(3, w)
    #undef GDSTEP
  }

  #pragma unroll
  for (int r = 0; r < 4; ++r) {
    int row = row0 + tr4 + r;
    if (row < nrows) {
      float4 ob = (r == 0) ? ab0 : (r == 1) ? ab1 : (r == 2) ? ab2 : ab3;
      float4 p = *(const float4*)&proj[(size_t)row * HID + tc4];
      p.x += ob.x; p.y += ob.y; p.z += ob.z; p.w += ob.w;
      if (HASW) {
        float s = ns[row];
        float4 o = (r == 0) ? aw0 : (r == 1) ? aw1 : (r == 2) ? aw2 : aw3;
        ushort4 pk;
        pk.x = f2bf(o.x * s); pk.y = f2bf(o.y * s); pk.z = f2bf(o.z * s); pk.w = f2bf(o.w * s);
        *(ushort4*)&hs[(size_t)row * HID + tc4] = pk;
        *(float4*)&proj[(size_t)row * HID + tc4] = p;
      } else {
        ushort4 pk;
        pk.x = f2bf(p.x); pk.y = f2bf(p.y); pk.z = f2bf(p.z); pk.w = f2bf(p.w);
        *(ushort4*)&hs[(size_t)row * HID + tc4] = pk;   // hs = final JK table (bf16)
      }
    }
  }
}

// ---- gather-sum over bf16 table: wave per node, 4 edge-groups x 16 lanes x (4 bf16 = 8B) ----
// FINAL=false: y = relu(acc*nd + b);  FINAL=true: y = acc + b (bout)
template<bool FINAL>
__global__ __launch_bounds__(256) void k_gather_bf(const int* __restrict__ row_start, const int* __restrict__ cnt,
                                                   const int* __restrict__ col, const unsigned short* __restrict__ x,
                                                   const float* __restrict__ nd, const float* __restrict__ b,
                                                   float* __restrict__ y, int n) {
  int node = blockIdx.x * 4 + (threadIdx.x >> 6);
  if (node >= n) return;
  int lane = threadIdx.x & 63;
  int g = lane >> 4;
  int fl = (lane & 15) * 4;
  int j0 = row_start[node];
  int jend = j0 + cnt[node];
  float4 acc = {0,0,0,0};
  for (int j = j0 + g; j < jend; j += 4) {
    int s = col[j];
    ushort4 u = *(const ushort4*)&x[(size_t)s * HID + fl];
    acc.x += bf2f(u.x); acc.y += bf2f(u.y); acc.z += bf2f(u.z); acc.w += bf2f(u.w);
  }
  #pragma unroll
  for (int m = 16; m <= 32; m <<= 1) {
    acc.x += __shfl_xor(acc.x, m, 64);
    acc.y += __shfl_xor(acc.y, m, 64);
    acc.z += __shfl_xor(acc.z, m, 64);
    acc.w += __shfl_xor(acc.w, m, 64);
  }
  if (g == 0) {
    float4 bb = *(const float4*)&b[fl];
    float4 o;
    if (FINAL) {
      o.x = acc.x + bb.x; o.y = acc.y + bb.y; o.z = acc.z + bb.z; o.w = acc.w + bb.w;
    } else {
      float s = nd[node];
      o.x = fmaxf(acc.x * s + bb.x, 0.f);
      o.y = fmaxf(acc.y * s + bb.y, 0.f);
      o.z = fmaxf(acc.z * s + bb.z, 0.f);
      o.w = fmaxf(acc.w * s + bb.w, 0.f);
    }
    *(float4*)&y[(size_t)node * HID + fl] = o;
  }
}

extern "C" void kernel_launch(void* const* d_in, const int* in_sizes, int n_in,
                              void* d_out, int out_size, void* d_ws, size_t ws_size,
                              hipStream_t stream) {
  const float* feats = (const float*)d_in[0];
  const int* src = (const int*)d_in[1];
  const int* dst = (const int*)d_in[2];
  const float* W[NLAYERS]    = {(const float*)d_in[3], (const float*)d_in[5], (const float*)d_in[7],
                                (const float*)d_in[9], (const float*)d_in[11]};
  const float* bias[NLAYERS] = {(const float*)d_in[4], (const float*)d_in[6], (const float*)d_in[8],
                                (const float*)d_in[10], (const float*)d_in[12]};
  const float* Wout = (const float*)d_in[13];
  const float* bout = (const float*)d_in[14];
  float* out = (float*)d_out;

  const int N = in_sizes[0] / FIN;
  const int E = in_sizes[1];
  const size_t Np = (size_t)((N + 63) / 64) * 64;
  const size_t Ep = (size_t)((E + 63) / 64) * 64;

  char* w = (char*)d_ws;
  int* cnt_s     = (int*)w;            w += Np * 4;
  int* cnt_d     = (int*)w;            w += Np * 4;
  int* row_start = (int*)w;            w += Np * 4;
  int* gcur      = (int*)w;            w += 64 * 4;
  int* col       = (int*)w;            w += Ep * 4;
  float* norm_s  = (float*)w;          w += Np * 4;
  float* norm_d  = (float*)w;          w += Np * 4;
  float* h       = (float*)w;          w += Np * HID * 4;
  float* proj    = (float*)w;          w += Np * HID * 4;
  unsigned short* hsbuf = (unsigned short*)w;  w += Np * HID * 2;
  // rank aliases h: rank used only during CSR build, h first written after k_place. Ep <= Np*64.
  int* rank = (int*)h;

  (void)hipMemsetAsync(cnt_s, 0, 2 * Np * sizeof(int), stream);
  (void)hipMemsetAsync(gcur, 0, sizeof(int), stream);
  (void)hipMemsetAsync(proj, 0, (size_t)N * HID * sizeof(float), stream);

  k_count<<<(E + 255) / 256, 256, 0, stream>>>(src, dst, cnt_s, cnt_d, rank, E);
  k_norm<<<(int)((2 * Np + 255) / 256), 256, 0, stream>>>(cnt_s, norm_s, (int)(2 * Np));
  k_rowalloc<<<(N + 255) / 256, 256, 0, stream>>>(cnt_d, row_start, gcur, N);
  k_place<<<(E + 255) / 256, 256, 0, stream>>>(src, dst, rank, row_start, col, E);

  const int GEMMB = (N + 63) / 64;
  k_gemm0<<<GEMMB, 256, 0, stream>>>(feats, norm_s, W[0], hsbuf, N);

  const int GB = (N + 3) / 4;
  for (int i = 0; i < NLAYERS; ++i) {
    k_gather_bf<false><<<GB, 256, 0, stream>>>(row_start, cnt_d, col, hsbuf, norm_d, bias[i], h, N);
    if (i < NLAYERS - 1) {
      k_gemm_dual<true><<<GEMMB, 256, 0, stream>>>(h, norm_s, W[i + 1], Wout + (size_t)i * HID * HID,
                                                   hsbuf, proj, N);
    } else {
      // last layer: hsbuf becomes the bf16 final JK projection table (proj + h@Wb)
      k_gemm_dual<false><<<GEMMB, 256, 0, stream>>>(h, norm_s, nullptr, Wout + (size_t)i * HID * HID,
                                                    hsbuf, proj, N);
    }
  }
  k_gather_bf<true><<<GB, 256, 0, stream>>>(row_start, cnt_d, col, hsbuf, nullptr, bout, out, N);
}

// Round 10
// 724.011 us; speedup vs baseline: 3.2864x; 1.0514x over previous
//
#include <hip/hip_runtime.h>

#define FIN 256
#define HID 64
#define NLAYERS 5

#define FMA4(ACC, S, V) { float _s = (S); ACC.x += _s*(V).x; ACC.y += _s*(V).y; ACC.z += _s*(V).z; ACC.w += _s*(V).w; }

__device__ inline unsigned short f2bf(float f) {            // round-to-nearest-even
  unsigned u = __float_as_uint(f);
  u += 0x7FFF + ((u >> 16) & 1);
  return (unsigned short)(u >> 16);
}
__device__ inline float bf2f(unsigned short s) { return __uint_as_float(((unsigned)s) << 16); }

// ---- count: dst histogram with returned rank ----
__global__ __launch_bounds__(256) void k_count(const int* __restrict__ dst,
                                               int* __restrict__ cd, int* __restrict__ rank, int E) {
  int i = blockIdx.x * 256 + threadIdx.x;
  if (i < E) rank[i] = atomicAdd(&cd[dst[i]], 1);
}

// ---- CSR row allocation: wave scan + one atomic per wave ----
__global__ __launch_bounds__(256) void k_rowalloc(const int* __restrict__ cnt, int* __restrict__ row_start,
                                                  int* __restrict__ gcur, int n) {
  int i = blockIdx.x * 256 + threadIdx.x;
  int lane = threadIdx.x & 63;
  int c = (i < n) ? cnt[i] : 0;
  int s = c;
  #pragma unroll
  for (int d = 1; d < 64; d <<= 1) {
    int t = __shfl_up(s, d, 64);
    if (lane >= d) s += t;
  }
  int total = __shfl(s, 63, 64);
  int base = 0;
  if (lane == 63) base = atomicAdd(gcur, total);
  base = __shfl(base, 63, 64);
  int start = base + s - c;
  if (i < n) row_start[i] = start;
}

// ---- place: atomic-free CSR fill + src (out-degree) histogram ----
__global__ __launch_bounds__(256) void k_place(const int* __restrict__ src, const int* __restrict__ dst,
                                               const int* __restrict__ rank, const int* __restrict__ row_start,
                                               int* __restrict__ col, int* __restrict__ cs, int E) {
  int e = blockIdx.x * 256 + threadIdx.x;
  if (e < E) {
    int s = src[e];
    col[row_start[dst[e]] + rank[e]] = s;
    atomicAdd(&cs[s], 1);
  }
}

__global__ __launch_bounds__(256) void k_norm(const int* __restrict__ cnt, float* __restrict__ nrm, int n) {
  int i = blockIdx.x * 256 + threadIdx.x;
  if (i < n) nrm[i] = rsqrtf(fmaxf((float)cnt[i], 1.0f));
}

// ---- gemm0: hs[row] = bf16( ns[row] * (feats[row] @ W0) ), 256->64 ----
#define G0PAD 36
__global__ __launch_bounds__(256) void k_gemm0(const float* __restrict__ feats, const float* __restrict__ ns,
                                               const float* __restrict__ W0, unsigned short* __restrict__ hs,
                                               int nrows) {
  __shared__ float sA[64 * G0PAD];
  __shared__ float sW[32 * 64];
  const int tid = threadIdx.x;
  const int row0 = blockIdx.x * 64;
  const int tr4 = (tid >> 4) * 4;
  const int tc4 = (tid & 15) * 4;
  const int sr = tid >> 3;
  const int sc = (tid & 7) * 4;
  const int wk = tid >> 3;
  float4 acc0 = {0,0,0,0}, acc1 = {0,0,0,0}, acc2 = {0,0,0,0}, acc3 = {0,0,0,0};
  const float4 z4 = {0,0,0,0};

  for (int kb = 0; kb < FIN; kb += 32) {
    __syncthreads();
    {
      int r1 = row0 + sr, r2 = row0 + sr + 32;
      float4 v1 = (r1 < nrows) ? *(const float4*)&feats[(size_t)r1 * FIN + kb + sc] : z4;
      float4 v2 = (r2 < nrows) ? *(const float4*)&feats[(size_t)r2 * FIN + kb + sc] : z4;
      *(float4*)&sA[sr * G0PAD + sc] = v1;
      *(float4*)&sA[(sr + 32) * G0PAD + sc] = v2;
      *(float4*)&sW[wk * 64 + sc]      = *(const float4*)&W0[(size_t)(kb + wk) * HID + sc];
      *(float4*)&sW[wk * 64 + sc + 32] = *(const float4*)&W0[(size_t)(kb + wk) * HID + sc + 32];
    }
    __syncthreads();
    #pragma unroll
    for (int kc = 0; kc < 32; kc += 4) {
      float4 a0 = *(const float4*)&sA[(tr4 + 0) * G0PAD + kc];
      float4 a1 = *(const float4*)&sA[(tr4 + 1) * G0PAD + kc];
      float4 a2 = *(const float4*)&sA[(tr4 + 2) * G0PAD + kc];
      float4 a3 = *(const float4*)&sA[(tr4 + 3) * G0PAD + kc];
      #define G0STEP(KK, C) { \
        float4 wv = *(const float4*)&sW[(kc + KK) * 64 + tc4]; \
        FMA4(acc0, a0.C, wv); FMA4(acc1, a1.C, wv); FMA4(acc2, a2.C, wv); FMA4(acc3, a3.C, wv); }
      G0STEP(0, x) G0STEP(1, y) G0STEP(2, z) G0STEP(3, w)
      #undef G0STEP
    }
  }
  #pragma unroll
  for (int r = 0; r < 4; ++r) {
    int row = row0 + tr4 + r;
    if (row < nrows) {
      float s = ns[row];
      float4 o = (r == 0) ? acc0 : (r == 1) ? acc1 : (r == 2) ? acc2 : acc3;
      ushort4 p;
      p.x = f2bf(o.x * s); p.y = f2bf(o.y * s); p.z = f2bf(o.z * s); p.w = f2bf(o.w * s);
      *(ushort4*)&hs[(size_t)row * HID + tc4] = p;
    }
  }
}

// ---- dual GEMM over bf16 h.  HASW: hs(bf16) = ns*(h@W); proj += h@Wb (FIRST: write, else read-add).
//      !HASW (last layer): hs(bf16) = bf16(proj + h@Wb)  [final JK table].
// launch_bounds(256,4) + unroll 2: keep VGPR <=128 (R4 post-mortem: spill -> 1.7GB traffic).
#define GDPAD 68
template<bool HASW, bool FIRST>
__global__ __launch_bounds__(256, 4) void k_gemm_dual(const unsigned short* __restrict__ h,
                                                      const float* __restrict__ ns,
                                                      const float* __restrict__ W, const float* __restrict__ Wb,
                                                      unsigned short* __restrict__ hs, float* __restrict__ proj,
                                                      int nrows) {
  __shared__ float sA[64 * GDPAD];
  __shared__ float sW[64 * 64];
  __shared__ float sWb[64 * 64];
  const int tid = threadIdx.x;
  const int row0 = blockIdx.x * 64;
  const int tr4 = (tid >> 4) * 4;
  const int tc4 = (tid & 15) * 4;
  const int sr = tid >> 2;
  const int scb = (tid & 3) * 16;
  const float4 z4 = {0,0,0,0};

  {
    int gr = row0 + sr;
    #pragma unroll
    for (int o = 0; o < 16; o += 4) {
      float4 v = z4;
      if (gr < nrows) {
        ushort4 u = *(const ushort4*)&h[(size_t)gr * HID + scb + o];
        v.x = bf2f(u.x); v.y = bf2f(u.y); v.z = bf2f(u.z); v.w = bf2f(u.w);
      }
      *(float4*)&sA[sr * GDPAD + scb + o] = v;
      if (HASW) *(float4*)&sW[sr * 64 + scb + o] = *(const float4*)&W[(size_t)sr * HID + scb + o];
      *(float4*)&sWb[sr * 64 + scb + o] = *(const float4*)&Wb[(size_t)sr * HID + scb + o];
    }
  }
  __syncthreads();

  float4 aw0 = {0,0,0,0}, aw1 = {0,0,0,0}, aw2 = {0,0,0,0}, aw3 = {0,0,0,0};
  float4 ab0 = {0,0,0,0}, ab1 = {0,0,0,0}, ab2 = {0,0,0,0}, ab3 = {0,0,0,0};
  #pragma unroll 2
  for (int kc = 0; kc < 64; kc += 4) {
    float4 a0 = *(const float4*)&sA[(tr4 + 0) * GDPAD + kc];
    float4 a1 = *(const float4*)&sA[(tr4 + 1) * GDPAD + kc];
    float4 a2 = *(const float4*)&sA[(tr4 + 2) * GDPAD + kc];
    float4 a3 = *(const float4*)&sA[(tr4 + 3) * GDPAD + kc];
    #define GDSTEP(KK, C) { \
      if (HASW) { \
        float4 wv = *(const float4*)&sW[(kc + KK) * 64 + tc4]; \
        FMA4(aw0, a0.C, wv); FMA4(aw1, a1.C, wv); FMA4(aw2, a2.C, wv); FMA4(aw3, a3.C, wv); } \
      { float4 wbv = *(const float4*)&sWb[(kc + KK) * 64 + tc4]; \
        FMA4(ab0, a0.C, wbv); FMA4(ab1, a1.C, wbv); FMA4(ab2, a2.C, wbv); FMA4(ab3, a3.C, wbv); } }
    GDSTEP(0, x) GDSTEP(1, y) GDSTEP(2, z) GDSTEP(3, w)
    #undef GDSTEP
  }

  #pragma unroll
  for (int r = 0; r < 4; ++r) {
    int row = row0 + tr4 + r;
    if (row < nrows) {
      float4 ob = (r == 0) ? ab0 : (r == 1) ? ab1 : (r == 2) ? ab2 : ab3;
      float4 p;
      if (FIRST) {
        p = ob;
      } else {
        p = *(const float4*)&proj[(size_t)row * HID + tc4];
        p.x += ob.x; p.y += ob.y; p.z += ob.z; p.w += ob.w;
      }
      if (HASW) {
        float s = ns[row];
        float4 o = (r == 0) ? aw0 : (r == 1) ? aw1 : (r == 2) ? aw2 : aw3;
        ushort4 pk;
        pk.x = f2bf(o.x * s); pk.y = f2bf(o.y * s); pk.z = f2bf(o.z * s); pk.w = f2bf(o.w * s);
        *(ushort4*)&hs[(size_t)row * HID + tc4] = pk;
        *(float4*)&proj[(size_t)row * HID + tc4] = p;
      } else {
        ushort4 pk;
        pk.x = f2bf(p.x); pk.y = f2bf(p.y); pk.z = f2bf(p.z); pk.w = f2bf(p.w);
        *(ushort4*)&hs[(size_t)row * HID + tc4] = pk;   // hs = final JK table (bf16)
      }
    }
  }
}

// ---- gather-sum over bf16 table: wave per node, 4 edge-groups x 16 lanes x (4 bf16 = 8B) ----
// FINAL=false: h(bf16) = relu(acc*nd + b);  FINAL=true: out(f32) = acc + bout
template<bool FINAL>
__global__ __launch_bounds__(256) void k_gather_bf(const int* __restrict__ row_start, const int* __restrict__ cnt,
                                                   const int* __restrict__ col, const unsigned short* __restrict__ x,
                                                   const float* __restrict__ nd, const float* __restrict__ b,
                                                   unsigned short* __restrict__ ybf, float* __restrict__ yf,
                                                   int n) {
  int node = blockIdx.x * 4 + (threadIdx.x >> 6);
  if (node >= n) return;
  int lane = threadIdx.x & 63;
  int g = lane >> 4;
  int fl = (lane & 15) * 4;
  int j0 = row_start[node];
  int jend = j0 + cnt[node];
  float4 acc = {0,0,0,0};
  for (int j = j0 + g; j < jend; j += 4) {
    int s = col[j];
    ushort4 u = *(const ushort4*)&x[(size_t)s * HID + fl];
    acc.x += bf2f(u.x); acc.y += bf2f(u.y); acc.z += bf2f(u.z); acc.w += bf2f(u.w);
  }
  #pragma unroll
  for (int m = 16; m <= 32; m <<= 1) {
    acc.x += __shfl_xor(acc.x, m, 64);
    acc.y += __shfl_xor(acc.y, m, 64);
    acc.z += __shfl_xor(acc.z, m, 64);
    acc.w += __shfl_xor(acc.w, m, 64);
  }
  if (g == 0) {
    float4 bb = *(const float4*)&b[fl];
    if (FINAL) {
      float4 o = {acc.x + bb.x, acc.y + bb.y, acc.z + bb.z, acc.w + bb.w};
      *(float4*)&yf[(size_t)node * HID + fl] = o;
    } else {
      float s = nd[node];
      ushort4 pk;
      pk.x = f2bf(fmaxf(acc.x * s + bb.x, 0.f));
      pk.y = f2bf(fmaxf(acc.y * s + bb.y, 0.f));
      pk.z = f2bf(fmaxf(acc.z * s + bb.z, 0.f));
      pk.w = f2bf(fmaxf(acc.w * s + bb.w, 0.f));
      *(ushort4*)&ybf[(size_t)node * HID + fl] = pk;
    }
  }
}

extern "C" void kernel_launch(void* const* d_in, const int* in_sizes, int n_in,
                              void* d_out, int out_size, void* d_ws, size_t ws_size,
                              hipStream_t stream) {
  const float* feats = (const float*)d_in[0];
  const int* src = (const int*)d_in[1];
  const int* dst = (const int*)d_in[2];
  const float* W[NLAYERS]    = {(const float*)d_in[3], (const float*)d_in[5], (const float*)d_in[7],
                                (const float*)d_in[9], (const float*)d_in[11]};
  const float* bias[NLAYERS] = {(const float*)d_in[4], (const float*)d_in[6], (const float*)d_in[8],
                                (const float*)d_in[10], (const float*)d_in[12]};
  const float* Wout = (const float*)d_in[13];
  const float* bout = (const float*)d_in[14];
  float* out = (float*)d_out;

  const int N = in_sizes[0] / FIN;
  const int E = in_sizes[1];
  const size_t Np = (size_t)((N + 63) / 64) * 64;
  const size_t Ep = (size_t)((E + 63) / 64) * 64;

  char* w = (char*)d_ws;
  int* cnt_s     = (int*)w;            w += Np * 4;
  int* cnt_d     = (int*)w;            w += Np * 4;
  int* row_start = (int*)w;            w += Np * 4;
  int* gcur      = (int*)w;            w += 64 * 4;
  int* col       = (int*)w;            w += Ep * 4;
  float* norm_s  = (float*)w;          w += Np * 4;
  float* norm_d  = (float*)w;          w += Np * 4;
  unsigned short* h = (unsigned short*)w;      w += Np * HID * 2;
  float* proj    = (float*)w;          w += Np * HID * 4;
  unsigned short* hsbuf = (unsigned short*)w;  w += Np * HID * 2;
  // rank aliases h: rank used only during CSR build; h first written after k_place. Ep*4 <= Np*HID*2.
  int* rank = (int*)h;

  (void)hipMemsetAsync(cnt_s, 0, 2 * Np * sizeof(int), stream);
  (void)hipMemsetAsync(gcur, 0, sizeof(int), stream);

  k_count<<<(E + 255) / 256, 256, 0, stream>>>(dst, cnt_d, rank, E);
  k_rowalloc<<<(N + 255) / 256, 256, 0, stream>>>(cnt_d, row_start, gcur, N);
  k_place<<<(E + 255) / 256, 256, 0, stream>>>(src, dst, rank, row_start, col, cnt_s, E);
  // norm_s|norm_d contiguous (Np-strided): one launch after cnt_s complete
  k_norm<<<(int)((2 * Np + 255) / 256), 256, 0, stream>>>(cnt_s, norm_s, (int)(2 * Np));

  const int GEMMB = (N + 63) / 64;
  k_gemm0<<<GEMMB, 256, 0, stream>>>(feats, norm_s, W[0], hsbuf, N);

  const int GB = (N + 3) / 4;
  for (int i = 0; i < NLAYERS; ++i) {
    k_gather_bf<false><<<GB, 256, 0, stream>>>(row_start, cnt_d, col, hsbuf, norm_d, bias[i], h, nullptr, N);
    const float* Wb = Wout + (size_t)i * HID * HID;
    if (i == 0) {
      k_gemm_dual<true, true><<<GEMMB, 256, 0, stream>>>(h, norm_s, W[1], Wb, hsbuf, proj, N);
    } else if (i < NLAYERS - 1) {
      k_gemm_dual<true, false><<<GEMMB, 256, 0, stream>>>(h, norm_s, W[i + 1], Wb, hsbuf, proj, N);
    } else {
      // last layer: hsbuf becomes the bf16 final JK projection table (proj + h@Wb)
      k_gemm_dual<false, false><<<GEMMB, 256, 0, stream>>>(h, norm_s, nullptr, Wb, hsbuf, proj, N);
    }
  }
  k_gather_bf<true><<<GB, 256, 0, stream>>>(row_start, cnt_d, col, hsbuf, nullptr, bout, nullptr, out, N);
}

// Round 11
// 638.176 us; speedup vs baseline: 3.7284x; 1.1345x over previous
//
#include <hip/hip_runtime.h>

#define FIN 256
#define HID 64
#define NLAYERS 5

#define FMA4(ACC, S, V) { float _s = (S); ACC.x += _s*(V).x; ACC.y += _s*(V).y; ACC.z += _s*(V).z; ACC.w += _s*(V).w; }

__device__ inline unsigned short f2bf(float f) {            // round-to-nearest-even
  unsigned u = __float_as_uint(f);
  u += 0x7FFF + ((u >> 16) & 1);
  return (unsigned short)(u >> 16);
}
__device__ inline float bf2f(unsigned short s) { return __uint_as_float(((unsigned)s) << 16); }

// ---- count: dst histogram with returned rank; 2 edges/thread for 2x outstanding atomics ----
__global__ __launch_bounds__(256) void k_count(const int* __restrict__ dst,
                                               int* __restrict__ cd, int* __restrict__ rank,
                                               int E, int half) {
  int i = blockIdx.x * 256 + threadIdx.x;
  if (i < half) rank[i] = atomicAdd(&cd[dst[i]], 1);
  int i2 = i + half;
  if (i2 < E) rank[i2] = atomicAdd(&cd[dst[i2]], 1);
}

// ---- CSR row allocation: wave scan + one atomic per wave ----
__global__ __launch_bounds__(256) void k_rowalloc(const int* __restrict__ cnt, int* __restrict__ row_start,
                                                  int* __restrict__ gcur, int n) {
  int i = blockIdx.x * 256 + threadIdx.x;
  int lane = threadIdx.x & 63;
  int c = (i < n) ? cnt[i] : 0;
  int s = c;
  #pragma unroll
  for (int d = 1; d < 64; d <<= 1) {
    int t = __shfl_up(s, d, 64);
    if (lane >= d) s += t;
  }
  int total = __shfl(s, 63, 64);
  int base = 0;
  if (lane == 63) base = atomicAdd(gcur, total);
  base = __shfl(base, 63, 64);
  int start = base + s - c;
  if (i < n) row_start[i] = start;
}

// ---- place: atomic-free CSR fill + src (out-degree) histogram ----
__global__ __launch_bounds__(256) void k_place(const int* __restrict__ src, const int* __restrict__ dst,
                                               const int* __restrict__ rank, const int* __restrict__ row_start,
                                               int* __restrict__ col, int* __restrict__ cs, int E) {
  int e = blockIdx.x * 256 + threadIdx.x;
  if (e < E) {
    int s = src[e];
    col[row_start[dst[e]] + rank[e]] = s;
    atomicAdd(&cs[s], 1);
  }
}

__global__ __launch_bounds__(256) void k_norm(const int* __restrict__ cnt, float* __restrict__ nrm, int n) {
  int i = blockIdx.x * 256 + threadIdx.x;
  if (i < n) nrm[i] = rsqrtf(fmaxf((float)cnt[i], 1.0f));
}

// ---- gemm0: hs[row] = bf16( ns[row] * (feats[row] @ W0) ), 256->64 ----
#define G0PAD 36
__global__ __launch_bounds__(256) void k_gemm0(const float* __restrict__ feats, const float* __restrict__ ns,
                                               const float* __restrict__ W0, unsigned short* __restrict__ hs,
                                               int nrows) {
  __shared__ float sA[64 * G0PAD];
  __shared__ float sW[32 * 64];
  const int tid = threadIdx.x;
  const int row0 = blockIdx.x * 64;
  const int tr4 = (tid >> 4) * 4;
  const int tc4 = (tid & 15) * 4;
  const int sr = tid >> 3;
  const int sc = (tid & 7) * 4;
  const int wk = tid >> 3;
  float4 acc0 = {0,0,0,0}, acc1 = {0,0,0,0}, acc2 = {0,0,0,0}, acc3 = {0,0,0,0};
  const float4 z4 = {0,0,0,0};

  for (int kb = 0; kb < FIN; kb += 32) {
    __syncthreads();
    {
      int r1 = row0 + sr, r2 = row0 + sr + 32;
      float4 v1 = (r1 < nrows) ? *(const float4*)&feats[(size_t)r1 * FIN + kb + sc] : z4;
      float4 v2 = (r2 < nrows) ? *(const float4*)&feats[(size_t)r2 * FIN + kb + sc] : z4;
      *(float4*)&sA[sr * G0PAD + sc] = v1;
      *(float4*)&sA[(sr + 32) * G0PAD + sc] = v2;
      *(float4*)&sW[wk * 64 + sc]      = *(const float4*)&W0[(size_t)(kb + wk) * HID + sc];
      *(float4*)&sW[wk * 64 + sc + 32] = *(const float4*)&W0[(size_t)(kb + wk) * HID + sc + 32];
    }
    __syncthreads();
    #pragma unroll
    for (int kc = 0; kc < 32; kc += 4) {
      float4 a0 = *(const float4*)&sA[(tr4 + 0) * G0PAD + kc];
      float4 a1 = *(const float4*)&sA[(tr4 + 1) * G0PAD + kc];
      float4 a2 = *(const float4*)&sA[(tr4 + 2) * G0PAD + kc];
      float4 a3 = *(const float4*)&sA[(tr4 + 3) * G0PAD + kc];
      #define G0STEP(KK, C) { \
        float4 wv = *(const float4*)&sW[(kc + KK) * 64 + tc4]; \
        FMA4(acc0, a0.C, wv); FMA4(acc1, a1.C, wv); FMA4(acc2, a2.C, wv); FMA4(acc3, a3.C, wv); }
      G0STEP(0, x) G0STEP(1, y) G0STEP(2, z) G0STEP(3, w)
      #undef G0STEP
    }
  }
  #pragma unroll
  for (int r = 0; r < 4; ++r) {
    int row = row0 + tr4 + r;
    if (row < nrows) {
      float s = ns[row];
      float4 o = (r == 0) ? acc0 : (r == 1) ? acc1 : (r == 2) ? acc2 : acc3;
      ushort4 p;
      p.x = f2bf(o.x * s); p.y = f2bf(o.y * s); p.z = f2bf(o.z * s); p.w = f2bf(o.w * s);
      *(ushort4*)&hs[(size_t)row * HID + tc4] = p;
    }
  }
}

// ---- dual GEMM over bf16 h.  HASW: hs(bf16) = ns*(h@W); proj += h@Wb (FIRST: write, else read-add).
//      !HASW (last layer): hs(bf16) = bf16(proj + h@Wb)  [final JK table].
// launch_bounds(256,4) + unroll 2: keep VGPR <=128 (R4 post-mortem: spill -> 1.7GB traffic).
#define GDPAD 68
template<bool HASW, bool FIRST>
__global__ __launch_bounds__(256, 4) void k_gemm_dual(const unsigned short* __restrict__ h,
                                                      const float* __restrict__ ns,
                                                      const float* __restrict__ W, const float* __restrict__ Wb,
                                                      unsigned short* __restrict__ hs, float* __restrict__ proj,
                                                      int nrows) {
  __shared__ float sA[64 * GDPAD];
  __shared__ float sW[64 * 64];
  __shared__ float sWb[64 * 64];
  const int tid = threadIdx.x;
  const int row0 = blockIdx.x * 64;
  const int tr4 = (tid >> 4) * 4;
  const int tc4 = (tid & 15) * 4;
  const int sr = tid >> 2;
  const int scb = (tid & 3) * 16;
  const float4 z4 = {0,0,0,0};

  {
    int gr = row0 + sr;
    #pragma unroll
    for (int o = 0; o < 16; o += 4) {
      float4 v = z4;
      if (gr < nrows) {
        ushort4 u = *(const ushort4*)&h[(size_t)gr * HID + scb + o];
        v.x = bf2f(u.x); v.y = bf2f(u.y); v.z = bf2f(u.z); v.w = bf2f(u.w);
      }
      *(float4*)&sA[sr * GDPAD + scb + o] = v;
      if (HASW) *(float4*)&sW[sr * 64 + scb + o] = *(const float4*)&W[(size_t)sr * HID + scb + o];
      *(float4*)&sWb[sr * 64 + scb + o] = *(const float4*)&Wb[(size_t)sr * HID + scb + o];
    }
  }
  __syncthreads();

  float4 aw0 = {0,0,0,0}, aw1 = {0,0,0,0}, aw2 = {0,0,0,0}, aw3 = {0,0,0,0};
  float4 ab0 = {0,0,0,0}, ab1 = {0,0,0,0}, ab2 = {0,0,0,0}, ab3 = {0,0,0,0};
  #pragma unroll 2
  for (int kc = 0; kc < 64; kc += 4) {
    float4 a0 = *(const float4*)&sA[(tr4 + 0) * GDPAD + kc];
    float4 a1 = *(const float4*)&sA[(tr4 + 1) * GDPAD + kc];
    float4 a2 = *(const float4*)&sA[(tr4 + 2) * GDPAD + kc];
    float4 a3 = *(const float4*)&sA[(tr4 + 3) * GDPAD + kc];
    #define GDSTEP(KK, C) { \
      if (HASW) { \
        float4 wv = *(const float4*)&sW[(kc + KK) * 64 + tc4]; \
        FMA4(aw0, a0.C, wv); FMA4(aw1, a1.C, wv); FMA4(aw2, a2.C, wv); FMA4(aw3, a3.C, wv); } \
      { float4 wbv = *(const float4*)&sWb[(kc + KK) * 64 + tc4]; \
        FMA4(ab0, a0.C, wbv); FMA4(ab1, a1.C, wbv); FMA4(ab2, a2.C, wbv); FMA4(ab3, a3.C, wbv); } }
    GDSTEP(0, x) GDSTEP(1, y) GDSTEP(2, z) GDSTEP(3, w)
    #undef GDSTEP
  }

  #pragma unroll
  for (int r = 0; r < 4; ++r) {
    int row = row0 + tr4 + r;
    if (row < nrows) {
      float4 ob = (r == 0) ? ab0 : (r == 1) ? ab1 : (r == 2) ? ab2 : ab3;
      float4 p;
      if (FIRST) {
        p = ob;
      } else {
        p = *(const float4*)&proj[(size_t)row * HID + tc4];
        p.x += ob.x; p.y += ob.y; p.z += ob.z; p.w += ob.w;
      }
      if (HASW) {
        float s = ns[row];
        float4 o = (r == 0) ? aw0 : (r == 1) ? aw1 : (r == 2) ? aw2 : aw3;
        ushort4 pk;
        pk.x = f2bf(o.x * s); pk.y = f2bf(o.y * s); pk.z = f2bf(o.z * s); pk.w = f2bf(o.w * s);
        *(ushort4*)&hs[(size_t)row * HID + tc4] = pk;
        *(float4*)&proj[(size_t)row * HID + tc4] = p;
      } else {
        ushort4 pk;
        pk.x = f2bf(p.x); pk.y = f2bf(p.y); pk.z = f2bf(p.z); pk.w = f2bf(p.w);
        *(ushort4*)&hs[(size_t)row * HID + tc4] = pk;   // hs = final JK table (bf16)
      }
    }
  }
}

// ---- gather-sum over bf16 table: wave per node, 4 edge-groups x 16 lanes x (4 bf16 = 8B) ----
// Unroll 2 with dual accumulators: 8 outstanding row-loads per wave (R10 post-mortem:
// gathers were MLP-latency-limited at ~4.2 TB/s with only 4 outstanding).
// FINAL=false: h(bf16) = relu(acc*nd + b);  FINAL=true: out(f32) = acc + bout
template<bool FINAL>
__global__ __launch_bounds__(256) void k_gather_bf(const int* __restrict__ row_start, const int* __restrict__ cnt,
                                                   const int* __restrict__ col, const unsigned short* __restrict__ x,
                                                   const float* __restrict__ nd, const float* __restrict__ b,
                                                   unsigned short* __restrict__ ybf, float* __restrict__ yf,
                                                   int n) {
  int node = blockIdx.x * 4 + (threadIdx.x >> 6);
  if (node >= n) return;
  int lane = threadIdx.x & 63;
  int g = lane >> 4;
  int fl = (lane & 15) * 4;
  int j0 = row_start[node];
  int jend = j0 + cnt[node];
  float4 acc = {0,0,0,0}, acc2 = {0,0,0,0};
  int j = j0 + g;
  for (; j + 4 < jend; j += 8) {
    int s1 = col[j];
    int s2 = col[j + 4];
    ushort4 u1 = *(const ushort4*)&x[(size_t)s1 * HID + fl];
    ushort4 u2 = *(const ushort4*)&x[(size_t)s2 * HID + fl];
    acc.x  += bf2f(u1.x); acc.y  += bf2f(u1.y); acc.z  += bf2f(u1.z); acc.w  += bf2f(u1.w);
    acc2.x += bf2f(u2.x); acc2.y += bf2f(u2.y); acc2.z += bf2f(u2.z); acc2.w += bf2f(u2.w);
  }
  if (j < jend) {
    int s = col[j];
    ushort4 u = *(const ushort4*)&x[(size_t)s * HID + fl];
    acc.x += bf2f(u.x); acc.y += bf2f(u.y); acc.z += bf2f(u.z); acc.w += bf2f(u.w);
  }
  acc.x += acc2.x; acc.y += acc2.y; acc.z += acc2.z; acc.w += acc2.w;
  #pragma unroll
  for (int m = 16; m <= 32; m <<= 1) {
    acc.x += __shfl_xor(acc.x, m, 64);
    acc.y += __shfl_xor(acc.y, m, 64);
    acc.z += __shfl_xor(acc.z, m, 64);
    acc.w += __shfl_xor(acc.w, m, 64);
  }
  if (g == 0) {
    float4 bb = *(const float4*)&b[fl];
    if (FINAL) {
      float4 o = {acc.x + bb.x, acc.y + bb.y, acc.z + bb.z, acc.w + bb.w};
      *(float4*)&yf[(size_t)node * HID + fl] = o;
    } else {
      float s = nd[node];
      ushort4 pk;
      pk.x = f2bf(fmaxf(acc.x * s + bb.x, 0.f));
      pk.y = f2bf(fmaxf(acc.y * s + bb.y, 0.f));
      pk.z = f2bf(fmaxf(acc.z * s + bb.z, 0.f));
      pk.w = f2bf(fmaxf(acc.w * s + bb.w, 0.f));
      *(ushort4*)&ybf[(size_t)node * HID + fl] = pk;
    }
  }
}

extern "C" void kernel_launch(void* const* d_in, const int* in_sizes, int n_in,
                              void* d_out, int out_size, void* d_ws, size_t ws_size,
                              hipStream_t stream) {
  const float* feats = (const float*)d_in[0];
  const int* src = (const int*)d_in[1];
  const int* dst = (const int*)d_in[2];
  const float* W[NLAYERS]    = {(const float*)d_in[3], (const float*)d_in[5], (const float*)d_in[7],
                                (const float*)d_in[9], (const float*)d_in[11]};
  const float* bias[NLAYERS] = {(const float*)d_in[4], (const float*)d_in[6], (const float*)d_in[8],
                                (const float*)d_in[10], (const float*)d_in[12]};
  const float* Wout = (const float*)d_in[13];
  const float* bout = (const float*)d_in[14];
  float* out = (float*)d_out;

  const int N = in_sizes[0] / FIN;
  const int E = in_sizes[1];
  const size_t Np = (size_t)((N + 63) / 64) * 64;
  const size_t Ep = (size_t)((E + 63) / 64) * 64;

  char* w = (char*)d_ws;
  int* cnt_s     = (int*)w;            w += Np * 4;
  int* cnt_d     = (int*)w;            w += Np * 4;
  int* row_start = (int*)w;            w += Np * 4;
  int* gcur      = (int*)w;            w += 64 * 4;
  int* col       = (int*)w;            w += Ep * 4;
  float* norm_s  = (float*)w;          w += Np * 4;
  float* norm_d  = (float*)w;          w += Np * 4;
  unsigned short* h = (unsigned short*)w;      w += Np * HID * 2;
  float* proj    = (float*)w;          w += Np * HID * 4;
  unsigned short* hsbuf = (unsigned short*)w;  w += Np * HID * 2;
  // rank aliases h: rank used only during CSR build; h first written after k_place. Ep*4 <= Np*HID*2.
  int* rank = (int*)h;

  (void)hipMemsetAsync(cnt_s, 0, 2 * Np * sizeof(int), stream);
  (void)hipMemsetAsync(gcur, 0, sizeof(int), stream);

  const int half = (E + 1) / 2;
  k_count<<<(half + 255) / 256, 256, 0, stream>>>(dst, cnt_d, rank, E, half);
  k_rowalloc<<<(N + 255) / 256, 256, 0, stream>>>(cnt_d, row_start, gcur, N);
  k_place<<<(E + 255) / 256, 256, 0, stream>>>(src, dst, rank, row_start, col, cnt_s, E);
  // norm_s|norm_d contiguous (Np-strided): one launch after cnt_s complete
  k_norm<<<(int)((2 * Np + 255) / 256), 256, 0, stream>>>(cnt_s, norm_s, (int)(2 * Np));

  const int GEMMB = (N + 63) / 64;
  k_gemm0<<<GEMMB, 256, 0, stream>>>(feats, norm_s, W[0], hsbuf, N);

  const int GB = (N + 3) / 4;
  for (int i = 0; i < NLAYERS; ++i) {
    k_gather_bf<false><<<GB, 256, 0, stream>>>(row_start, cnt_d, col, hsbuf, norm_d, bias[i], h, nullptr, N);
    const float* Wb = Wout + (size_t)i * HID * HID;
    if (i == 0) {
      k_gemm_dual<true, true><<<GEMMB, 256, 0, stream>>>(h, norm_s, W[1], Wb, hsbuf, proj, N);
    } else if (i < NLAYERS - 1) {
      k_gemm_dual<true, false><<<GEMMB, 256, 0, stream>>>(h, norm_s, W[i + 1], Wb, hsbuf, proj, N);
    } else {
      // last layer: hsbuf becomes the bf16 final JK projection table (proj + h@Wb)
      k_gemm_dual<false, false><<<GEMMB, 256, 0, stream>>>(h, norm_s, nullptr, Wb, hsbuf, proj, N);
    }
  }
  k_gather_bf<true><<<GB, 256, 0, stream>>>(row_start, cnt_d, col, hsbuf, nullptr, bout, nullptr, out, N);
}